// Round 10
// baseline (355.235 us; speedup 1.0000x reference)
//
#include <hip/hip_runtime.h>
#include <hip/hip_bf16.h>

// Problem constants
#define CC 768
#define MM 32768                // pixels (8*64*64)
#define NQKV 2304               // 3*CC
#define SCALE_ 0.125f           // 64^-0.5

typedef __bf16 bf16x8 __attribute__((ext_vector_type(8)));
typedef float f32x4 __attribute__((ext_vector_type(4)));
typedef unsigned short ushort8_t __attribute__((ext_vector_type(8)));

static __device__ __forceinline__ float bf2f(unsigned short u) {
  return __uint_as_float(((unsigned int)u) << 16);
}
static __device__ __forceinline__ unsigned short f2bf(float f) {
  __hip_bfloat16 t = __float2bfloat16(f);
  return __builtin_bit_cast(unsigned short, t);
}

#define FENCE() asm volatile("" ::: "memory")
#define GLDS(src, dst) __builtin_amdgcn_global_load_lds( \
    (const __attribute__((address_space(1))) void*)(src), \
    (__attribute__((address_space(3))) void*)(dst), 16, 0, 0)

// ---------------------------------------------------------------------------
// fused f32 -> bf16 convert over the 3 input regions (x, qkv_w, proj_w).
// ---------------------------------------------------------------------------
#define N4_X     (MM * CC / 4)
#define N4_WQKV  (NQKV * CC / 4)
#define N4_WPROJ (CC * CC / 4)

__global__ void cvt3_kernel(const float* __restrict__ x,
                            const float* __restrict__ qw,
                            const float* __restrict__ pw,
                            __hip_bfloat16* __restrict__ xb,
                            __hip_bfloat16* __restrict__ wqkvb,
                            __hip_bfloat16* __restrict__ wprojb) {
  int i = blockIdx.x * blockDim.x + threadIdx.x;
  const float* in;
  __hip_bfloat16* out;
  if (i < N4_X) {
    in = x; out = xb;
  } else if (i < N4_X + N4_WQKV) {
    i -= N4_X; in = qw; out = wqkvb;
  } else {
    i -= N4_X + N4_WQKV; i -= 0; in = pw; out = wprojb;
  }
  float4 v = reinterpret_cast<const float4*>(in)[i];
  ushort4 o;
  o.x = f2bf(v.x); o.y = f2bf(v.y); o.z = f2bf(v.z); o.w = f2bf(v.w);
  reinterpret_cast<ushort4*>(out)[i] = o;
}

// ---------------------------------------------------------------------------
// bf16 GEMM (R9-proven): D = A[M][K] * Bw[N][K]^T. 128x128 tile, BK=32,
// 4 waves (2x2). Depth-2 counted-vmcnt pipeline (3 LDS buffer sets);
// conflict-free swizzled staging (rule #21); XCD-aware block swizzle.
// MODE 1: bf16 TRANSPOSED outT[N][M] via LDS-transposed COALESCED epilogue.
// MODE 2: f32 out[M][N] + bias (row-major).
// ---------------------------------------------------------------------------
template <int MODE>
__global__ __launch_bounds__(256) void gemm_bf16_kernel(
    const __hip_bfloat16* __restrict__ A,
    const __hip_bfloat16* __restrict__ Bw,
    void* __restrict__ outp,
    const float* __restrict__ bias,
    int M, int N, int K) {
  __shared__ __hip_bfloat16 lds[2][3][128 * 32];

  const int nBN = N >> 7;
  const int cpx = gridDim.x >> 3;
  const int bid = ((int)blockIdx.x & 7) * cpx + ((int)blockIdx.x >> 3);
  const int bm = bid / nBN;
  const int bn = bid % nBN;
  const int tid = threadIdx.x;
  const int lane = tid & 63;
  const int wv = tid >> 6;
  const int wr = wv >> 1;
  const int wc = wv & 1;

  f32x4 acc[4][4] = {};

  const int srow = wv * 16 + (lane >> 2);
  const int scol = ((lane & 3) ^ ((lane >> 3) & 3)) * 8;
  const size_t Abase = (size_t)(bm * 128) * K;
  const size_t Bbase = (size_t)(bn * 128) * K;

  const int frow = lane & 15;
  const int g = lane >> 4;
  const int fcol = (g ^ ((frow >> 1) & 3)) * 8;

  auto stage = [&](int buf, int t) {
    const int k0 = t << 5;
#pragma unroll
    for (int c = 0; c < 2; ++c) {
      const __hip_bfloat16* gA = A + Abase + (size_t)(c * 64 + srow) * K + k0 + scol;
      GLDS(gA, &lds[0][buf][(c * 64 + wv * 16) * 32]);
      const __hip_bfloat16* gB = Bw + Bbase + (size_t)(c * 64 + srow) * K + k0 + scol;
      GLDS(gB, &lds[1][buf][(c * 64 + wv * 16) * 32]);
    }
  };

  const int nt = K >> 5;                     // 24 for K=768
  stage(0, 0);
  if (nt > 1) stage(1, 1);

  int rd = 0;
  int st = 2;
  for (int t = 0; t < nt; ++t) {
    if (t + 1 < nt) asm volatile("s_waitcnt vmcnt(4)" ::: "memory");
    else            asm volatile("s_waitcnt vmcnt(0)" ::: "memory");
    __builtin_amdgcn_s_barrier();
    FENCE();

    bf16x8 af[4], bfr[4];
#pragma unroll
    for (int m = 0; m < 4; ++m)
      af[m] = *reinterpret_cast<const bf16x8*>(&lds[0][rd][(wr * 64 + m * 16 + frow) * 32 + fcol]);
#pragma unroll
    for (int n = 0; n < 4; ++n)
      bfr[n] = *reinterpret_cast<const bf16x8*>(&lds[1][rd][(wc * 64 + n * 16 + frow) * 32 + fcol]);

    if (t + 2 < nt) stage(st, t + 2);

#pragma unroll
    for (int m = 0; m < 4; ++m)
#pragma unroll
      for (int n = 0; n < 4; ++n)
        acc[m][n] = __builtin_amdgcn_mfma_f32_16x16x32_bf16(af[m], bfr[n], acc[m][n], 0, 0, 0);

    rd = (rd == 2) ? 0 : rd + 1;
    st = (st == 2) ? 0 : st + 1;
  }

  // C/D layout: col = lane&15, row = (lane>>4)*4 + r   [m89]
  const int r0 = (lane >> 4) * 4;
  const int cc_ = lane & 15;

  if (MODE == 1) {
    __syncthreads();
    unsigned short* tb =
        reinterpret_cast<unsigned short*>(&lds[0][0][0]) + wv * 4608;
#pragma unroll
    for (int m = 0; m < 4; ++m) {
#pragma unroll
      for (int n = 0; n < 4; ++n) {
        ushort4 pk;
        pk.x = f2bf(acc[m][n][0]);
        pk.y = f2bf(acc[m][n][1]);
        pk.z = f2bf(acc[m][n][2]);
        pk.w = f2bf(acc[m][n][3]);
        *reinterpret_cast<ushort4*>(tb + (n * 16 + cc_) * 72 + m * 16 + r0) = pk;
      }
    }
    const int j = lane >> 3;
    const int k = lane & 7;
    __hip_bfloat16* outT = (__hip_bfloat16*)outp;
    const int gcol0 = bn * 128 + wc * 64;
    const int grow0 = bm * 128 + wr * 64 + k * 8;
#pragma unroll
    for (int rr = 0; rr < 8; ++rr) {
      const ushort8_t v =
          *reinterpret_cast<const ushort8_t*>(tb + (rr * 8 + j) * 72 + k * 8);
      *reinterpret_cast<ushort8_t*>(
          outT + (size_t)(gcol0 + rr * 8 + j) * M + grow0) = v;
    }
  } else {
#pragma unroll
    for (int m = 0; m < 4; ++m) {
#pragma unroll
      for (int n = 0; n < 4; ++n) {
        const int grow = bm * 128 + wr * 64 + m * 16 + r0;
        const int gcol = bn * 128 + wc * 64 + n * 16 + cc_;
        float* outF = (float*)outp;
        const float bv = bias ? bias[gcol] : 0.f;
#pragma unroll
        for (int r = 0; r < 4; ++r)
          outF[(size_t)(grow + r) * N + gcol] = acc[m][n][r] + bv;
      }
    }
  }
}

// ---------------------------------------------------------------------------
// Dilated local attention v4: cooperative-QK merged block.
// Block = 512 threads = one head x 256 pixels; half = tid>>8 owns 32 channels.
// Each half computes a 32-ch partial QK dot (320 loads, not 640), halves
// exchange the 9 partial logits via LDS, sum, softmax (redundant, cheap),
// then PV + residual over own 32 channels (R5 pattern).
// OOB taps: logit 0 in denominator path, 0 weight in numerator (zero-pad ref).
// OOB reads land inside workspace (adjacent planes).
// ---------------------------------------------------------------------------
__global__ __launch_bounds__(512) void attn_kernel(
    const unsigned short* __restrict__ qkvT,
    const unsigned short* __restrict__ xres,
    unsigned short* __restrict__ y) {
  __shared__ float part[9][2][256];

  const int head = blockIdx.x >> 7;            // 0..11 (uniform per block)
  const int tid = threadIdx.x;
  const int half = tid >> 8;                   // 0: ch 0-31, 1: ch 32-63
  const int pidx = tid & 255;
  const int p = ((blockIdx.x & 127) << 8) + pidx;         // pixel
  const int h = (p >> 6) & 63;
  const int w = p & 63;
  const int grp = head >> 2;
  const int dil = grp + 1;                     // DILATIONS = (1,2,3)
  const int chq = grp * 256 + (head & 3) * 64;
  const int chh = chq + half * 32;             // this thread's 32-ch range

  int voff[9];
  bool valid[9];
#pragma unroll
  for (int t = 0; t < 9; ++t) {
    const int di = t / 3 - 1, dj = t % 3 - 1;
    valid[t] = ((unsigned)(h + di * dil) < 64u) && ((unsigned)(w + dj * dil) < 64u);
    voff[t] = p + (di * 64 + dj) * dil + 256;  // +256 bias keeps index >= 0
  }
  const int voffq = p + 256;

  // ---- QK phase: 32-ch partial dot, batched 4 channels at a time ----
  const unsigned short* qb = qkvT + (size_t)chh * MM - 256;
  const unsigned short* kb = qkvT + (size_t)(768 + chh) * MM - 256;

  float l[9] = {};
#pragma unroll 1
  for (int cb = 0; cb < 8; ++cb) {
    unsigned short qv[4];
    unsigned short kv[4][9];
#pragma unroll
    for (int i = 0; i < 4; ++i) qv[i] = qb[voffq + i * MM];
#pragma unroll
    for (int i = 0; i < 4; ++i)
#pragma unroll
      for (int t = 0; t < 9; ++t) kv[i][t] = kb[voff[t] + i * MM];
#pragma unroll
    for (int i = 0; i < 4; ++i) {
      const float qf = bf2f(qv[i]);
#pragma unroll
      for (int t = 0; t < 9; ++t)
        l[t] = fmaf(qf, bf2f(kv[i][t]), l[t]);
    }
    qb += 4 * MM;
    kb += 4 * MM;
  }

  // ---- exchange partials between halves ----
#pragma unroll
  for (int t = 0; t < 9; ++t) part[t][half][pidx] = l[t];
  __syncthreads();
#pragma unroll
  for (int t = 0; t < 9; ++t) l[t] += part[t][half ^ 1][pidx];

  // ---- softmax (computed redundantly by both halves) ----
#pragma unroll
  for (int t = 0; t < 9; ++t) l[t] = valid[t] ? l[t] * SCALE_ : 0.f;
  float mx = l[0];
#pragma unroll
  for (int t = 1; t < 9; ++t) mx = fmaxf(mx, l[t]);
  float den = 0.f;
#pragma unroll
  for (int t = 0; t < 9; ++t) {
    const float e = __expf(l[t] - mx);
    den += e;                                  // invalid taps count in denom
    l[t] = valid[t] ? e : 0.f;                 // but contribute 0 to numerator
  }
  const float inv = 1.f / den;
#pragma unroll
  for (int t = 0; t < 9; ++t) l[t] *= inv;

  // ---- PV phase: own 32 channels, batched 4 at a time ----
  const unsigned short* vb = qkvT + (size_t)(1536 + chh) * MM - 256;
  float vout[32];
#pragma unroll 1
  for (int cb = 0; cb < 8; ++cb) {
    unsigned short vv[4][9];
#pragma unroll
    for (int i = 0; i < 4; ++i)
#pragma unroll
      for (int t = 0; t < 9; ++t) vv[i][t] = vb[voff[t] + i * MM];
#pragma unroll
    for (int i = 0; i < 4; ++i) {
      float acc = 0.f;
#pragma unroll
      for (int t = 0; t < 9; ++t)
        acc = fmaf(l[t], bf2f(vv[i][t]), acc);
      vout[cb * 4 + i] = acc;
    }
    vb += 4 * MM;
  }

  // ---- residual (bf16) + pack + store: 4 x 16B contiguous per thread ----
  const ushort8_t* xr = reinterpret_cast<const ushort8_t*>(xres + (size_t)p * CC + chh);
  ushort8_t* yr = reinterpret_cast<ushort8_t*>(y + (size_t)p * CC + chh);
#pragma unroll
  for (int k = 0; k < 4; ++k) {
    const ushort8_t xa = xr[k];
    ushort8_t o;
#pragma unroll
    for (int j = 0; j < 8; ++j)
      o[j] = f2bf(vout[8 * k + j] + bf2f(xa[j]));
    yr[k] = o;
  }
}

// ---------------------------------------------------------------------------
// launch
// ---------------------------------------------------------------------------
extern "C" void kernel_launch(void* const* d_in, const int* in_sizes, int n_in,
                              void* d_out, int out_size, void* d_ws, size_t ws_size,
                              hipStream_t stream) {
  const float* x = (const float*)d_in[0];
  const float* qkv_w = (const float*)d_in[1];
  const float* proj_w = (const float*)d_in[2];
  const float* proj_b = (const float*)d_in[3];
  float* out = (float*)d_out;

  char* ws = (char*)d_ws;
  // ws layout (bytes), total 206,045,184:
  //   [0, 50331648)            xb [M][768] bf16  -> reused as y [M][768] bf16
  //   [50331648, 201326592)    qkvT [2304][M] bf16
  //   [201326592, 204865536)   wqkvb [2304][768] bf16 (absorbs OOB tap reads)
  //   [204865536, 206045184)   wprojb [768][768] bf16
  __hip_bfloat16* xb = (__hip_bfloat16*)(ws);
  __hip_bfloat16* qkvT = (__hip_bfloat16*)(ws + 50331648);
  __hip_bfloat16* wqkvb = (__hip_bfloat16*)(ws + 201326592);
  __hip_bfloat16* wprojb = (__hip_bfloat16*)(ws + 204865536);
  __hip_bfloat16* ybuf = xb;                   // y overwrites xb (per-thread
                                               // read-then-write, exclusive)

  // fused f32->bf16 converts: (6291456 + 442368 + 147456) / 256 = 26880 blocks
  cvt3_kernel<<<(N4_X + N4_WQKV + N4_WPROJ) / 256, 256, 0, stream>>>(
      x, qkv_w, proj_w, xb, wqkvb, wprojb);

  // qkv GEMM -> channel-major qkvT [2304][M]   (grid 4608 % 8 == 0)
  gemm_bf16_kernel<1><<<(MM / 128) * (NQKV / 128), 256, 0, stream>>>(
      xb, wqkvb, (void*)qkvT, nullptr, MM, NQKV, CC);

  // attention + residual -> y [M][768] bf16 (12 heads x 128 px-blocks, 512thr)
  attn_kernel<<<12 * 128, 512, 0, stream>>>(
      (const unsigned short*)qkvT, (const unsigned short*)xb,
      (unsigned short*)ybuf);

  // proj GEMM -> f32 out [M][768] + bias      (grid 1536 % 8 == 0)
  gemm_bf16_kernel<2><<<(MM / 128) * (CC / 128), 256, 0, stream>>>(
      ybuf, wprojb, (void*)out, proj_b, MM, CC, CC);
}

// Round 11
// 350.430 us; speedup vs baseline: 1.0137x; 1.0137x over previous
//
#include <hip/hip_runtime.h>
#include <hip/hip_bf16.h>

// Problem constants
#define CC 768
#define MM 32768                // pixels (8*64*64)
#define NQKV 2304               // 3*CC
#define SCALE_ 0.125f           // 64^-0.5

typedef __bf16 bf16x8 __attribute__((ext_vector_type(8)));
typedef float f32x4 __attribute__((ext_vector_type(4)));
typedef unsigned short ushort8_t __attribute__((ext_vector_type(8)));

static __device__ __forceinline__ float bf2f(unsigned short u) {
  return __uint_as_float(((unsigned int)u) << 16);
}
static __device__ __forceinline__ unsigned short f2bf(float f) {
  __hip_bfloat16 t = __float2bfloat16(f);
  return __builtin_bit_cast(unsigned short, t);
}

#define FENCE() asm volatile("" ::: "memory")
#define GLDS(src, dst) __builtin_amdgcn_global_load_lds( \
    (const __attribute__((address_space(1))) void*)(src), \
    (__attribute__((address_space(3))) void*)(dst), 16, 0, 0)

// ---------------------------------------------------------------------------
// fused f32 -> bf16 convert over the 3 input regions (x, qkv_w, proj_w).
// ---------------------------------------------------------------------------
#define N4_X     (MM * CC / 4)
#define N4_WQKV  (NQKV * CC / 4)
#define N4_WPROJ (CC * CC / 4)

__global__ void cvt3_kernel(const float* __restrict__ x,
                            const float* __restrict__ qw,
                            const float* __restrict__ pw,
                            __hip_bfloat16* __restrict__ xb,
                            __hip_bfloat16* __restrict__ wqkvb,
                            __hip_bfloat16* __restrict__ wprojb) {
  int i = blockIdx.x * blockDim.x + threadIdx.x;
  const float* in;
  __hip_bfloat16* out;
  if (i < N4_X) {
    in = x; out = xb;
  } else if (i < N4_X + N4_WQKV) {
    i -= N4_X; in = qw; out = wqkvb;
  } else {
    i -= N4_X + N4_WQKV; in = pw; out = wprojb;
  }
  float4 v = reinterpret_cast<const float4*>(in)[i];
  ushort4 o;
  o.x = f2bf(v.x); o.y = f2bf(v.y); o.z = f2bf(v.z); o.w = f2bf(v.w);
  reinterpret_cast<ushort4*>(out)[i] = o;
}

// ---------------------------------------------------------------------------
// bf16 GEMM (R9-proven): D = A[M][K] * Bw[N][K]^T. 128x128 tile, BK=32,
// 4 waves (2x2). Depth-2 counted-vmcnt pipeline (3 LDS buffer sets);
// conflict-free swizzled staging (rule #21); XCD-aware block swizzle.
// MODE 1: bf16 TRANSPOSED outT[N][M] via LDS-transposed COALESCED epilogue:
//   wave writes its 64x64 C-subtile col-major (stride 72) into the dead
//   staging LDS, reads back ushort8 chunks, stores 128B-contiguous runs
//   per outT column (8 lanes x 16B).
// MODE 2: f32 out[M][N] + bias (row-major).
// ---------------------------------------------------------------------------
template <int MODE>
__global__ __launch_bounds__(256) void gemm_bf16_kernel(
    const __hip_bfloat16* __restrict__ A,
    const __hip_bfloat16* __restrict__ Bw,
    void* __restrict__ outp,
    const float* __restrict__ bias,
    int M, int N, int K) {
  __shared__ __hip_bfloat16 lds[2][3][128 * 32];

  const int nBN = N >> 7;
  const int cpx = gridDim.x >> 3;
  const int bid = ((int)blockIdx.x & 7) * cpx + ((int)blockIdx.x >> 3);
  const int bm = bid / nBN;
  const int bn = bid % nBN;
  const int tid = threadIdx.x;
  const int lane = tid & 63;
  const int wv = tid >> 6;
  const int wr = wv >> 1;
  const int wc = wv & 1;

  f32x4 acc[4][4] = {};

  const int srow = wv * 16 + (lane >> 2);
  const int scol = ((lane & 3) ^ ((lane >> 3) & 3)) * 8;
  const size_t Abase = (size_t)(bm * 128) * K;
  const size_t Bbase = (size_t)(bn * 128) * K;

  const int frow = lane & 15;
  const int g = lane >> 4;
  const int fcol = (g ^ ((frow >> 1) & 3)) * 8;

  auto stage = [&](int buf, int t) {
    const int k0 = t << 5;
#pragma unroll
    for (int c = 0; c < 2; ++c) {
      const __hip_bfloat16* gA = A + Abase + (size_t)(c * 64 + srow) * K + k0 + scol;
      GLDS(gA, &lds[0][buf][(c * 64 + wv * 16) * 32]);
      const __hip_bfloat16* gB = Bw + Bbase + (size_t)(c * 64 + srow) * K + k0 + scol;
      GLDS(gB, &lds[1][buf][(c * 64 + wv * 16) * 32]);
    }
  };

  const int nt = K >> 5;                     // 24 for K=768
  stage(0, 0);
  if (nt > 1) stage(1, 1);

  int rd = 0;
  int st = 2;
  for (int t = 0; t < nt; ++t) {
    if (t + 1 < nt) asm volatile("s_waitcnt vmcnt(4)" ::: "memory");
    else            asm volatile("s_waitcnt vmcnt(0)" ::: "memory");
    __builtin_amdgcn_s_barrier();
    FENCE();

    bf16x8 af[4], bfr[4];
#pragma unroll
    for (int m = 0; m < 4; ++m)
      af[m] = *reinterpret_cast<const bf16x8*>(&lds[0][rd][(wr * 64 + m * 16 + frow) * 32 + fcol]);
#pragma unroll
    for (int n = 0; n < 4; ++n)
      bfr[n] = *reinterpret_cast<const bf16x8*>(&lds[1][rd][(wc * 64 + n * 16 + frow) * 32 + fcol]);

    if (t + 2 < nt) stage(st, t + 2);

#pragma unroll
    for (int m = 0; m < 4; ++m)
#pragma unroll
      for (int n = 0; n < 4; ++n)
        acc[m][n] = __builtin_amdgcn_mfma_f32_16x16x32_bf16(af[m], bfr[n], acc[m][n], 0, 0, 0);

    rd = (rd == 2) ? 0 : rd + 1;
    st = (st == 2) ? 0 : st + 1;
  }

  // C/D layout: col = lane&15, row = (lane>>4)*4 + r   [m89]
  const int r0 = (lane >> 4) * 4;
  const int cc_ = lane & 15;

  if (MODE == 1) {
    __syncthreads();
    unsigned short* tb =
        reinterpret_cast<unsigned short*>(&lds[0][0][0]) + wv * 4608;
#pragma unroll
    for (int m = 0; m < 4; ++m) {
#pragma unroll
      for (int n = 0; n < 4; ++n) {
        ushort4 pk;
        pk.x = f2bf(acc[m][n][0]);
        pk.y = f2bf(acc[m][n][1]);
        pk.z = f2bf(acc[m][n][2]);
        pk.w = f2bf(acc[m][n][3]);
        *reinterpret_cast<ushort4*>(tb + (n * 16 + cc_) * 72 + m * 16 + r0) = pk;
      }
    }
    const int j = lane >> 3;
    const int k = lane & 7;
    __hip_bfloat16* outT = (__hip_bfloat16*)outp;
    const int gcol0 = bn * 128 + wc * 64;
    const int grow0 = bm * 128 + wr * 64 + k * 8;
#pragma unroll
    for (int rr = 0; rr < 8; ++rr) {
      const ushort8_t v =
          *reinterpret_cast<const ushort8_t*>(tb + (rr * 8 + j) * 72 + k * 8);
      *reinterpret_cast<ushort8_t*>(
          outT + (size_t)(gcol0 + rr * 8 + j) * M + grow0) = v;
    }
  } else {
#pragma unroll
    for (int m = 0; m < 4; ++m) {
#pragma unroll
      for (int n = 0; n < 4; ++n) {
        const int grow = bm * 128 + wr * 64 + m * 16 + r0;
        const int gcol = bn * 128 + wc * 64 + n * 16 + cc_;
        float* outF = (float*)outp;
        const float bv = bias ? bias[gcol] : 0.f;
#pragma unroll
        for (int r = 0; r < 4; ++r)
          outF[(size_t)(grow + r) * N + gcol] = acc[m][n][r] + bv;
      }
    }
  }
}

// ---------------------------------------------------------------------------
// Dilated local attention (R5/R9-proven): thread = (pixel, head, half).
//  - channel-split x2: vout[32], 12288 waves
//  - explicit load batching (4 channels/batch): ~40 independent ushort loads
//    in flight per wave
//  - residual read from bf16 xb; y aliases xb (exclusive per-thread range)
// OOB taps: logit 0 in denominator, 0 in numerator (zero-pad reference).
// OOB reads land inside workspace (adjacent planes / weight region).
// ---------------------------------------------------------------------------
__global__ __launch_bounds__(256) void attn_kernel(
    const unsigned short* __restrict__ qkvT,
    const unsigned short* __restrict__ xres,
    unsigned short* __restrict__ y) {
  const int hh = blockIdx.x >> 7;              // 0..23 (uniform per block)
  const int head = hh >> 1;
  const int half = hh & 1;
  const int p = ((blockIdx.x & 127) << 8) + threadIdx.x;  // pixel
  const int h = (p >> 6) & 63;
  const int w = p & 63;
  const int grp = head >> 2;
  const int dil = grp + 1;                     // DILATIONS = (1,2,3)
  const int chq = grp * 256 + (head & 3) * 64;

  int voff[9];
  bool valid[9];
#pragma unroll
  for (int t = 0; t < 9; ++t) {
    const int di = t / 3 - 1, dj = t % 3 - 1;
    valid[t] = ((unsigned)(h + di * dil) < 64u) && ((unsigned)(w + dj * dil) < 64u);
    voff[t] = p + (di * 64 + dj) * dil + 256;  // +256 bias keeps index >= 0
  }
  const int voffq = p + 256;

  const unsigned short* qb = qkvT + (size_t)chq * MM - 256;
  const unsigned short* kb = qkvT + (size_t)(768 + chq) * MM - 256;

  float l[9] = {};
#pragma unroll 1
  for (int cb = 0; cb < 16; ++cb) {
    unsigned short qv[4];
    unsigned short kv[4][9];
#pragma unroll
    for (int i = 0; i < 4; ++i) qv[i] = qb[voffq + i * MM];
#pragma unroll
    for (int i = 0; i < 4; ++i)
#pragma unroll
      for (int t = 0; t < 9; ++t) kv[i][t] = kb[voff[t] + i * MM];
#pragma unroll
    for (int i = 0; i < 4; ++i) {
      const float qf = bf2f(qv[i]);
#pragma unroll
      for (int t = 0; t < 9; ++t)
        l[t] = fmaf(qf, bf2f(kv[i][t]), l[t]);
    }
    qb += 4 * MM;
    kb += 4 * MM;
  }

#pragma unroll
  for (int t = 0; t < 9; ++t) l[t] = valid[t] ? l[t] * SCALE_ : 0.f;
  float mx = l[0];
#pragma unroll
  for (int t = 1; t < 9; ++t) mx = fmaxf(mx, l[t]);
  float den = 0.f;
#pragma unroll
  for (int t = 0; t < 9; ++t) {
    const float e = __expf(l[t] - mx);
    den += e;                                  // invalid taps count in denom
    l[t] = valid[t] ? e : 0.f;                 // but contribute 0 to numerator
  }
  const float inv = 1.f / den;
#pragma unroll
  for (int t = 0; t < 9; ++t) l[t] *= inv;

  const int cho = chq + half * 32;
  const unsigned short* vb = qkvT + (size_t)(1536 + cho) * MM - 256;
  float vout[32];
#pragma unroll 1
  for (int cb = 0; cb < 8; ++cb) {
    unsigned short vv[4][9];
#pragma unroll
    for (int i = 0; i < 4; ++i)
#pragma unroll
      for (int t = 0; t < 9; ++t) vv[i][t] = vb[voff[t] + i * MM];
#pragma unroll
    for (int i = 0; i < 4; ++i) {
      float acc = 0.f;
#pragma unroll
      for (int t = 0; t < 9; ++t)
        acc = fmaf(l[t], bf2f(vv[i][t]), acc);
      vout[cb * 4 + i] = acc;
    }
    vb += 4 * MM;
  }

  const ushort8_t* xr = reinterpret_cast<const ushort8_t*>(xres + (size_t)p * CC + cho);
  ushort8_t* yr = reinterpret_cast<ushort8_t*>(y + (size_t)p * CC + cho);
#pragma unroll
  for (int k = 0; k < 4; ++k) {
    const ushort8_t xa = xr[k];
    ushort8_t o;
#pragma unroll
    for (int j = 0; j < 8; ++j)
      o[j] = f2bf(vout[8 * k + j] + bf2f(xa[j]));
    yr[k] = o;
  }
}

// ---------------------------------------------------------------------------
// launch
// ---------------------------------------------------------------------------
extern "C" void kernel_launch(void* const* d_in, const int* in_sizes, int n_in,
                              void* d_out, int out_size, void* d_ws, size_t ws_size,
                              hipStream_t stream) {
  const float* x = (const float*)d_in[0];
  const float* qkv_w = (const float*)d_in[1];
  const float* proj_w = (const float*)d_in[2];
  const float* proj_b = (const float*)d_in[3];
  float* out = (float*)d_out;

  char* ws = (char*)d_ws;
  // ws layout (bytes), total 206,045,184:
  //   [0, 50331648)            xb [M][768] bf16  -> reused as y [M][768] bf16
  //   [50331648, 201326592)    qkvT [2304][M] bf16
  //   [201326592, 204865536)   wqkvb [2304][768] bf16 (absorbs OOB tap reads)
  //   [204865536, 206045184)   wprojb [768][768] bf16
  __hip_bfloat16* xb = (__hip_bfloat16*)(ws);
  __hip_bfloat16* qkvT = (__hip_bfloat16*)(ws + 50331648);
  __hip_bfloat16* wqkvb = (__hip_bfloat16*)(ws + 201326592);
  __hip_bfloat16* wprojb = (__hip_bfloat16*)(ws + 204865536);
  __hip_bfloat16* ybuf = xb;                   // y overwrites xb (per-thread
                                               // read-then-write, exclusive)

  // fused f32->bf16 converts: (6291456 + 442368 + 147456) / 256 = 26880 blocks
  cvt3_kernel<<<(N4_X + N4_WQKV + N4_WPROJ) / 256, 256, 0, stream>>>(
      x, qkv_w, proj_w, xb, wqkvb, wprojb);

  // qkv GEMM -> channel-major qkvT [2304][M]   (grid 4608 % 8 == 0)
  gemm_bf16_kernel<1><<<(MM / 128) * (NQKV / 128), 256, 0, stream>>>(
      xb, wqkvb, (void*)qkvT, nullptr, MM, NQKV, CC);

  // attention + residual -> y [M][768] bf16 (24 head-halves x 128 pixel-blocks)
  attn_kernel<<<24 * 128, 256, 0, stream>>>(
      (const unsigned short*)qkvT, (const unsigned short*)xb,
      (unsigned short*)ybuf);

  // proj GEMM -> f32 out [M][768] + bias      (grid 1536 % 8 == 0)
  gemm_bf16_kernel<2><<<(MM / 128) * (CC / 128), 256, 0, stream>>>(
      ybuf, wprojb, (void*)out, proj_b, MM, CC, CC);
}